// Round 4
// baseline (147.264 us; speedup 1.0000x reference)
//
#include <hip/hip_runtime.h>

#define NBINS 1001
#define HIST_BLOCK 256
#define VPT 8                                     // float4s of x (and of y) per thread per tile
#define TILES 2
#define TILE_ELEMS (HIST_BLOCK * VPT * 4)         // 8192
#define ELEMS_PER_BLOCK (TILE_ELEMS * TILES)      // 16384 -> 1024 blocks
#define NREP 8                                    // histogram replicas (flush-storm spreading)

typedef float fvec4 __attribute__((ext_vector_type(4)));   // clang vector: ok for nontemporal builtins

__device__ __forceinline__ int bin_of(float v) {
    // idx = #{ j in [0,999] : fp32(j/999) < v } ~= clamp(ceil(999*v), 0, 1000)
    // fp32 rounding flips a bin only when 999*v is within ~6e-5 of an integer
    // (~1e3 of 16.7M elems); each flip moves F1 by ~1e-6 << 1.08e-2 tolerance.
    int k = (int)ceilf(v * 999.0f);
    k = (k < 0) ? 0 : k;
    k = (k > 1000) ? 1000 : k;
    return k;
}

// Round-4 change vs the 144.6 µs kernel: NREP=8 global-histogram replicas.
// Rationale: 1024 blocks are ALL co-resident (4/CU) and run in lockstep, so
// the flush is a synchronized storm: 1.02M u64 atomics onto 500 cache lines
// (2048 same-line serialized RMWs per class-line ~= 4-8 µs un-overlapped
// tail). Block b flushes replica b&7 -> per-line contention drops 8x.
// f1 sums the replicas (bit-identical histogram).
__global__ __launch_bounds__(HIST_BLOCK) void hist_kernel(
    const float* __restrict__ x, const float* __restrict__ y,
    unsigned long long* __restrict__ ghist, int HW, int rep_mask)
{
    __shared__ unsigned int lh[NBINS];
    const int tid = threadIdx.x;

    const long long start = (long long)blockIdx.x * ELEMS_PER_BLOCK;
    const int c = (int)((start / HW) & 3);   // 16384 | HW=262144: block is class-uniform
    unsigned long long* __restrict__ gh =
        ghist + (size_t)(blockIdx.x & rep_mask) * 4 * NBINS + (size_t)c * NBINS;

    const fvec4* __restrict__ x4 = (const fvec4*)(x + start);
    const fvec4* __restrict__ y4 = (const fvec4*)(y + start);

    // Issue tile 0's whole memory phase first (single-use data -> nontemporal).
    fvec4 xv[VPT], yv[VPT];
    #pragma unroll
    for (int k = 0; k < VPT; ++k) {
        const int idx = k * HIST_BLOCK + tid;    // lanes contiguous: coalesced
        xv[k] = __builtin_nontemporal_load(&x4[idx]);
        yv[k] = __builtin_nontemporal_load(&y4[idx]);
    }

    // LDS init + barrier overlap the in-flight loads.
    for (int i = tid; i < NBINS; i += HIST_BLOCK) lh[i] = 0u;
    __syncthreads();

    #pragma unroll
    for (int t = 0; t < TILES; ++t) {
        #pragma unroll
        for (int k = 0; k < VPT; ++k) {
            const fvec4 xa = xv[k], ya = yv[k];
            if (t + 1 < TILES) {
                // reload this slot for the next tile; load latency hides
                // under the remaining atomics of the current tile
                const int idx = (t + 1) * (VPT * HIST_BLOCK) + k * HIST_BLOCK + tid;
                xv[k] = __builtin_nontemporal_load(&x4[idx]);
                yv[k] = __builtin_nontemporal_load(&y4[idx]);
            }
            // y is exactly 0.0f or 1.0f: bits(1.0f)=0x3f800000 -> (>>8)&0x10000
            atomicAdd(&lh[bin_of(xa.x)], 1u + ((__float_as_uint(ya.x) >> 8) & 0x10000u));
            atomicAdd(&lh[bin_of(xa.y)], 1u + ((__float_as_uint(ya.y) >> 8) & 0x10000u));
            atomicAdd(&lh[bin_of(xa.z)], 1u + ((__float_as_uint(ya.z) >> 8) & 0x10000u));
            atomicAdd(&lh[bin_of(xa.w)], 1u + ((__float_as_uint(ya.w) >> 8) & 0x10000u));
        }
    }
    __syncthreads();

    // Flush: unpack u32 -> u64 (low32 = count, high32 = positive count).
    // Fire-and-forget atomics: waves retire with them in flight; completion
    // overlaps across blocks at dispatch level (do NOT add a trailing sync).
    for (int i = tid; i < NBINS; i += HIST_BLOCK) {
        unsigned int v = lh[i];
        if (v) {
            unsigned long long add = (unsigned long long)(v & 0xffffu)
                                   | ((unsigned long long)(v >> 16) << 32);
            atomicAdd(&gh[i], add);
        }
    }
}

// One block, 1024 threads; thread t owns bin t for all 4 classes.
__global__ __launch_bounds__(1024) void f1_kernel(
    const unsigned long long* __restrict__ ghist, float* __restrict__ out, int nrep)
{
    __shared__ unsigned long long wtot[4][16];
    __shared__ float wmax[4][16];
    const int tid  = threadIdx.x;
    const int lane = tid & 63;
    const int wave = tid >> 6;

    unsigned long long v[4] = {0ULL, 0ULL, 0ULL, 0ULL};
    if (tid < NBINS) {
        for (int r = 0; r < nrep; ++r) {
            const unsigned long long* g = ghist + (size_t)r * 4 * NBINS;
            #pragma unroll
            for (int c = 0; c < 4; ++c)
                v[c] += g[(size_t)c * NBINS + tid];
        }
    }

    // intra-wave inclusive scan (u64, packed cnt | ycnt<<32 - fields can't interact)
    #pragma unroll
    for (int off = 1; off < 64; off <<= 1) {
        #pragma unroll
        for (int c = 0; c < 4; ++c) {
            unsigned long long t = __shfl_up(v[c], off, 64);
            if (lane >= off) v[c] += t;
        }
    }
    if (lane == 63) {
        #pragma unroll
        for (int c = 0; c < 4; ++c) wtot[c][wave] = v[c];
    }
    __syncthreads();

    // wave 0: inclusive scan of the 16 wave totals per class (lane = c*16 + w)
    if (wave == 0) {
        const int c = lane >> 4, w = lane & 15;
        unsigned long long t = wtot[c][w];
        #pragma unroll
        for (int off = 1; off < 16; off <<= 1) {
            unsigned long long s = __shfl_up(t, off, 16);
            if (w >= off) t += s;
        }
        wtot[c][w] = t;
    }
    __syncthreads();

    float m[4];
    #pragma unroll
    for (int c = 0; c < 4; ++c) {
        unsigned long long cum = v[c];
        if (wave > 0) cum += wtot[c][wave - 1];
        unsigned long long tot = wtot[c][15];
        unsigned int total_cnt = (unsigned int)(tot & 0xffffffffULL);  // N per class
        unsigned int total_y   = (unsigned int)(tot >> 32);
        float f1 = 0.0f;
        if (tid < NBINS - 1) {  // thresholds k = 0..999
            unsigned int cnt_cum = (unsigned int)(cum & 0xffffffffULL);
            unsigned int y_cum   = (unsigned int)(cum >> 32);
            unsigned int TP = total_y - y_cum;
            unsigned int PP = total_cnt - cnt_cum;
            unsigned int denom = total_y + PP;  // = 2*(TP + 0.5*(FN+FP))
            f1 = (denom == 0u) ? 0.0f : (2.0f * (float)TP) / (float)denom;
        }
        m[c] = f1;
    }

    // wave max-reduce per class
    #pragma unroll
    for (int off = 32; off > 0; off >>= 1) {
        #pragma unroll
        for (int c = 0; c < 4; ++c)
            m[c] = fmaxf(m[c], __shfl_down(m[c], off, 64));
    }
    if (lane == 0) {
        #pragma unroll
        for (int c = 0; c < 4; ++c) wmax[c][wave] = m[c];
    }
    __syncthreads();

    if (tid == 0) {
        float loss = 0.0f;
        #pragma unroll
        for (int c = 0; c < 4; ++c) {
            float mm = wmax[c][0];
            #pragma unroll
            for (int w = 1; w < 16; ++w) mm = fmaxf(mm, wmax[c][w]);
            loss += 1.0f - mm;
        }
        out[0] = loss * 0.25f;
    }
}

extern "C" void kernel_launch(void* const* d_in, const int* in_sizes, int n_in,
                              void* d_out, int out_size, void* d_ws, size_t ws_size,
                              hipStream_t stream) {
    const float* x = (const float*)d_in[0];
    const float* y = (const float*)d_in[1];
    float* out = (float*)d_out;

    const int H = 512, W = 512;
    const int HW = H * W;
    const long long total = (long long)in_sizes[0];   // 16777216

    unsigned long long* ghist = (unsigned long long*)d_ws;

    // Fall back to a single replica if the workspace is unexpectedly small.
    const int nrep = (ws_size >= (size_t)NREP * 4 * NBINS * sizeof(unsigned long long))
                         ? NREP : 1;

    (void)hipMemsetAsync(d_ws, 0,
                         (size_t)nrep * 4 * NBINS * sizeof(unsigned long long), stream);

    const int nblocks = (int)(total / ELEMS_PER_BLOCK);  // 1024
    hist_kernel<<<nblocks, HIST_BLOCK, 0, stream>>>(x, y, ghist, HW, nrep - 1);
    f1_kernel<<<1, 1024, 0, stream>>>(ghist, out, nrep);
    (void)n_in; (void)out_size;
}

// Round 5
// 144.538 us; speedup vs baseline: 1.0189x; 1.0189x over previous
//
#include <hip/hip_runtime.h>

#define NBINS 1001
#define HIST_BLOCK 256
#define VPT 8                                     // float4s of x (and of y) per thread per tile
#define TILES 2
#define TILE_ELEMS (HIST_BLOCK * VPT * 4)         // 8192
#define ELEMS_PER_BLOCK (TILE_ELEMS * TILES)      // 16384 -> 1024 blocks

typedef float fvec4 __attribute__((ext_vector_type(4)));   // clang vector: ok for nontemporal builtins

__device__ __forceinline__ int bin_of(float v) {
    // idx = #{ j in [0,999] : fp32(j/999) < v } ~= clamp(ceil(999*v), 0, 1000)
    // fp32 rounding flips a bin only when 999*v is within ~6e-5 of an integer
    // (~1e3 of 16.7M elems); each flip moves F1 by ~1e-6 << 1.08e-2 tolerance.
    int k = (int)ceilf(v * 999.0f);
    k = (k < 0) ? 0 : k;
    k = (k > 1000) ? 1000 : k;
    return k;
}

// FINAL (revert of round-4 NREP=8 replicas, which regressed 144.6 -> 147.3:
// the flush storm was already overlapped at dispatch level; replicas only
// added memset footprint and 8x replica reads in f1).
//
// Measured ladder on this problem:
//   - 2048 x 8192, 3 dispatches ................. 147.2 us  (round 0 baseline)
//   - fused single-kernel + ticket .............. 246.8 us  (VGPR 36, drain on
//     every block's critical path -- rejected)
//   - 1024 x 16384, 2-tile pipelined loads ...... 144.6 us  (BEST, this file)
//   - + 8 histogram replicas .................... 147.3 us  (rejected)
//
// ~111 us of dur_us is harness re-poison (256-MiB fills at 6.6 TB/s visible
// in rocprof top-5); the controllable slice is ~33 us vs a ~26 us floor
// (134 MB reads @ 6.6 TB/s + launch latency + the LDS-atomic scatter that
// partially hides under them).
//
// Structure: ALL 16 nontemporal float4 loads of tile 0 issued before the LDS
// init barrier (16 KB outstanding per wave through the barrier); tile-1
// loads reissued slot-by-slot under tile-0's LDS atomics so the pipeline
// never drains. Packed u32 bins: low16 = count, high16 = positive count
// (16384 elems/block < 2^16 -> no overflow). One LDS atomic per element is
// the scatter minimum. Flush atomics are fire-and-forget.
__global__ __launch_bounds__(HIST_BLOCK) void hist_kernel(
    const float* __restrict__ x, const float* __restrict__ y,
    unsigned long long* __restrict__ ghist, int HW)
{
    __shared__ unsigned int lh[NBINS];
    const int tid = threadIdx.x;

    const long long start = (long long)blockIdx.x * ELEMS_PER_BLOCK;
    const int c = (int)((start / HW) & 3);   // 16384 | HW=262144: block is class-uniform

    const fvec4* __restrict__ x4 = (const fvec4*)(x + start);
    const fvec4* __restrict__ y4 = (const fvec4*)(y + start);

    // Issue tile 0's whole memory phase first (single-use data -> nontemporal).
    fvec4 xv[VPT], yv[VPT];
    #pragma unroll
    for (int k = 0; k < VPT; ++k) {
        const int idx = k * HIST_BLOCK + tid;    // lanes contiguous: coalesced
        xv[k] = __builtin_nontemporal_load(&x4[idx]);
        yv[k] = __builtin_nontemporal_load(&y4[idx]);
    }

    // LDS init + barrier overlap the in-flight loads.
    for (int i = tid; i < NBINS; i += HIST_BLOCK) lh[i] = 0u;
    __syncthreads();

    #pragma unroll
    for (int t = 0; t < TILES; ++t) {
        #pragma unroll
        for (int k = 0; k < VPT; ++k) {
            const fvec4 xa = xv[k], ya = yv[k];
            if (t + 1 < TILES) {
                // reload this slot for the next tile; load latency hides
                // under the remaining atomics of the current tile
                const int idx = (t + 1) * (VPT * HIST_BLOCK) + k * HIST_BLOCK + tid;
                xv[k] = __builtin_nontemporal_load(&x4[idx]);
                yv[k] = __builtin_nontemporal_load(&y4[idx]);
            }
            // y is exactly 0.0f or 1.0f: bits(1.0f)=0x3f800000 -> (>>8)&0x10000
            atomicAdd(&lh[bin_of(xa.x)], 1u + ((__float_as_uint(ya.x) >> 8) & 0x10000u));
            atomicAdd(&lh[bin_of(xa.y)], 1u + ((__float_as_uint(ya.y) >> 8) & 0x10000u));
            atomicAdd(&lh[bin_of(xa.z)], 1u + ((__float_as_uint(ya.z) >> 8) & 0x10000u));
            atomicAdd(&lh[bin_of(xa.w)], 1u + ((__float_as_uint(ya.w) >> 8) & 0x10000u));
        }
    }
    __syncthreads();

    // Flush: unpack u32 -> u64 (low32 = count, high32 = positive count).
    // Fire-and-forget atomics: waves retire with them in flight; completion
    // overlaps across blocks at dispatch level (do NOT add a trailing sync).
    for (int i = tid; i < NBINS; i += HIST_BLOCK) {
        unsigned int v = lh[i];
        if (v) {
            unsigned long long add = (unsigned long long)(v & 0xffffu)
                                   | ((unsigned long long)(v >> 16) << 32);
            atomicAdd(&ghist[(size_t)c * NBINS + i], add);
        }
    }
}

// One block, 1024 threads; thread t owns bin t for all 4 classes.
__global__ __launch_bounds__(1024) void f1_kernel(
    const unsigned long long* __restrict__ ghist, float* __restrict__ out)
{
    __shared__ unsigned long long wtot[4][16];
    __shared__ float wmax[4][16];
    const int tid  = threadIdx.x;
    const int lane = tid & 63;
    const int wave = tid >> 6;

    unsigned long long v[4];
    #pragma unroll
    for (int c = 0; c < 4; ++c)
        v[c] = (tid < NBINS) ? ghist[(size_t)c * NBINS + tid] : 0ULL;

    // intra-wave inclusive scan (u64, packed cnt | ycnt<<32 - fields can't interact)
    #pragma unroll
    for (int off = 1; off < 64; off <<= 1) {
        #pragma unroll
        for (int c = 0; c < 4; ++c) {
            unsigned long long t = __shfl_up(v[c], off, 64);
            if (lane >= off) v[c] += t;
        }
    }
    if (lane == 63) {
        #pragma unroll
        for (int c = 0; c < 4; ++c) wtot[c][wave] = v[c];
    }
    __syncthreads();

    // wave 0: inclusive scan of the 16 wave totals per class (lane = c*16 + w)
    if (wave == 0) {
        const int c = lane >> 4, w = lane & 15;
        unsigned long long t = wtot[c][w];
        #pragma unroll
        for (int off = 1; off < 16; off <<= 1) {
            unsigned long long s = __shfl_up(t, off, 16);
            if (w >= off) t += s;
        }
        wtot[c][w] = t;
    }
    __syncthreads();

    float m[4];
    #pragma unroll
    for (int c = 0; c < 4; ++c) {
        unsigned long long cum = v[c];
        if (wave > 0) cum += wtot[c][wave - 1];
        unsigned long long tot = wtot[c][15];
        unsigned int total_cnt = (unsigned int)(tot & 0xffffffffULL);  // N per class
        unsigned int total_y   = (unsigned int)(tot >> 32);
        float f1 = 0.0f;
        if (tid < NBINS - 1) {  // thresholds k = 0..999
            unsigned int cnt_cum = (unsigned int)(cum & 0xffffffffULL);
            unsigned int y_cum   = (unsigned int)(cum >> 32);
            unsigned int TP = total_y - y_cum;
            unsigned int PP = total_cnt - cnt_cum;
            unsigned int denom = total_y + PP;  // = 2*(TP + 0.5*(FN+FP))
            f1 = (denom == 0u) ? 0.0f : (2.0f * (float)TP) / (float)denom;
        }
        m[c] = f1;
    }

    // wave max-reduce per class
    #pragma unroll
    for (int off = 32; off > 0; off >>= 1) {
        #pragma unroll
        for (int c = 0; c < 4; ++c)
            m[c] = fmaxf(m[c], __shfl_down(m[c], off, 64));
    }
    if (lane == 0) {
        #pragma unroll
        for (int c = 0; c < 4; ++c) wmax[c][wave] = m[c];
    }
    __syncthreads();

    if (tid == 0) {
        float loss = 0.0f;
        #pragma unroll
        for (int c = 0; c < 4; ++c) {
            float mm = wmax[c][0];
            #pragma unroll
            for (int w = 1; w < 16; ++w) mm = fmaxf(mm, wmax[c][w]);
            loss += 1.0f - mm;
        }
        out[0] = loss * 0.25f;
    }
}

extern "C" void kernel_launch(void* const* d_in, const int* in_sizes, int n_in,
                              void* d_out, int out_size, void* d_ws, size_t ws_size,
                              hipStream_t stream) {
    const float* x = (const float*)d_in[0];
    const float* y = (const float*)d_in[1];
    float* out = (float*)d_out;

    const int H = 512, W = 512;
    const int HW = H * W;
    const long long total = (long long)in_sizes[0];   // 16777216

    unsigned long long* ghist = (unsigned long long*)d_ws;

    (void)hipMemsetAsync(d_ws, 0, (size_t)4 * NBINS * sizeof(unsigned long long), stream);

    const int nblocks = (int)(total / ELEMS_PER_BLOCK);  // 1024
    hist_kernel<<<nblocks, HIST_BLOCK, 0, stream>>>(x, y, ghist, HW);
    f1_kernel<<<1, 1024, 0, stream>>>(ghist, out);
    (void)n_in; (void)out_size; (void)ws_size;
}